// Round 5
// baseline (262.439 us; speedup 1.0000x reference)
//
#include <hip/hip_runtime.h>
#include <math.h>

// EMA along T: y[0]=x[0]; y[t] = (1-a)*y[t-1] + a*x[t], a=0.01.
//
// 2-phase chunked scan. Key change this round: eliminate the serial FMA
// chain everywhere it isn't mathematically required. Round-3 counters
// showed VGPR_Count=28 -> the compiler kept ~no loads in flight because
// every load fed a sequential chain.
//  - Phase 1 chunk-end is a WEIGHTED SUM (compile-time weights
//    a*0.99^(63-t)), computed with 4 independent accumulators: pure
//    streaming reduction, should run at read-BW like the 84%-peak fills.
//  - Phase 2 carry fold (k>W) is also a weighted sum over W=16 ends.
//  - Phase 2 apply keeps the true recurrence but uses an explicit
//    register double-buffer (2x8 float4, statically indexed) so ~8 loads
//    stay in flight across the chain.
// W=16 chunks = 1024-step lookback: truncation 0.99^1024*|S|max ~ 1e-5,
// ~300x below the accepted absmax; EXACT for k<=W (ends[0] = true S_0).
// Round-3 counters proved phase-2's x re-read L3-hits (FETCH 139MB for a
// 2x-reader) with NT out-stores -> HBM traffic already ~256MB floor.
// Round 3 also proved per-block cross-XCD fences/spins run at 1.3 TB/s:
// single-pass decoupled lookback is a dead end on this chip.

namespace {
constexpr int B = 8;
constexpr int T = 8192;
constexpr int C = 512;
constexpr float ALPHA = 0.01f;
constexpr float DECAY = 1.0f - ALPHA;   // 0.99
constexpr int S4 = C / 4;               // float4 per timestep = 128
constexpr int TPB = S4;                 // 128 threads, 4 channels each
constexpr int CHUNK = 64;               // timesteps per block
constexpr int K = T / CHUNK;            // 128 chunks -> grid (128,8)
constexpr int W = 16;                   // lookback chunks (1024 steps)

typedef float f32x4 __attribute__((ext_vector_type(4)));

// 0.99^n folded at compile time (constexpr loop; float, matches device math).
constexpr float dpow(int n) {
    float r = 1.0f;
    for (int i = 0; i < n; ++i) r *= DECAY;
    return r;
}

__device__ __forceinline__ void ema_step(float4& y, const float4 v) {
    y.x = DECAY * y.x + ALPHA * v.x;
    y.y = DECAY * y.y + ALPHA * v.y;
    y.z = DECAY * y.z + ALPHA * v.z;
    y.w = DECAY * y.w + ALPHA * v.w;
}

__device__ __forceinline__ void wsum(float4& a, const float w, const float4 v) {
    a.x += w * v.x;
    a.y += w * v.y;
    a.z += w * v.z;
    a.w += w * v.w;
}
}

// Phase 1: per-chunk end-state as a weighted reduction (no serial chain).
// k>0:  E_k = sum_t  a*0.99^(CHUNK-1-t) * x[t]           (local sum L_k)
// k==0: x0's weight becomes 0.99^(CHUNK-1) (true init y[0]=x[0]), i.e.
//       add (1-a)*0.99^(CHUNK-1)*x0 on top of the generic sum.
__global__ __launch_bounds__(TPB) void ema_ends(const float* __restrict__ x,
                                                float* __restrict__ ends) {
    const int k = blockIdx.x;
    const int b = blockIdx.y;
    const int tid = threadIdx.x;
    const float4* xp = reinterpret_cast<const float4*>(x) +
                       (size_t)(b * T + k * CHUNK) * S4 + tid;
    float4 a0 = make_float4(0.f, 0.f, 0.f, 0.f);
    float4 a1 = a0, a2 = a0, a3 = a0;
    float4 x0;
#pragma unroll
    for (int t = 0; t < CHUNK; t += 4) {
        float4 v0 = xp[(size_t)(t + 0) * S4];
        float4 v1 = xp[(size_t)(t + 1) * S4];
        float4 v2 = xp[(size_t)(t + 2) * S4];
        float4 v3 = xp[(size_t)(t + 3) * S4];
        if (t == 0) x0 = v0;
        wsum(a0, ALPHA * dpow(CHUNK - 1 - (t + 0)), v0);
        wsum(a1, ALPHA * dpow(CHUNK - 1 - (t + 1)), v1);
        wsum(a2, ALPHA * dpow(CHUNK - 1 - (t + 2)), v2);
        wsum(a3, ALPHA * dpow(CHUNK - 1 - (t + 3)), v3);
    }
    float4 y;
    y.x = (a0.x + a1.x) + (a2.x + a3.x);
    y.y = (a0.y + a1.y) + (a2.y + a3.y);
    y.z = (a0.z + a1.z) + (a2.z + a3.z);
    y.w = (a0.w + a1.w) + (a2.w + a3.w);
    if (k == 0) {
        constexpr float e0 = (1.0f - ALPHA) * dpow(CHUNK - 1);
        y.x += e0 * x0.x; y.y += e0 * x0.y; y.z += e0 * x0.z; y.w += e0 * x0.w;
    }
    reinterpret_cast<float4*>(ends)[(size_t)(b * K + k) * S4 + tid] = y;
}

// Phase 2: carry (weighted sum over W=16 ends, compile-time weights) +
// apply (true recurrence, register-double-buffered loads, NT stores).
__global__ __launch_bounds__(TPB) void ema_apply(const float* __restrict__ x,
                                                 const float* __restrict__ ends,
                                                 float* __restrict__ out) {
    const int k = blockIdx.x;
    const int b = blockIdx.y;
    const int tid = threadIdx.x;
    const size_t base4 = (size_t)(b * T + k * CHUNK) * S4 + tid;
    const float4* xp = reinterpret_cast<const float4*>(x) + base4;
    float4* op = reinterpret_cast<float4*>(out) + base4;
    const float4* ep = reinterpret_cast<const float4*>(ends) +
                       (size_t)b * K * S4 + tid;

    // Issue the first x group early; carry fold overlaps with it.
    float4 buf[2][8];
#pragma unroll
    for (int i = 0; i < 8; ++i) buf[0][i] = xp[(size_t)i * S4];

    float4 y;
    if (k == 0) {
        y = buf[0][0];  // pre-state x0: loop then yields y[0] = x[0]
    } else if (k > W) {
        // carry = sum_{j=0}^{W-1} (0.99^CHUNK)^j * E_{k-1-j}; 4 indep accums.
        float4 c0 = make_float4(0.f, 0.f, 0.f, 0.f);
        float4 c1 = c0, c2 = c0, c3 = c0;
#pragma unroll
        for (int j = 0; j < W; j += 4) {
            float4 e0 = ep[(size_t)(k - 1 - (j + 0)) * S4];
            float4 e1 = ep[(size_t)(k - 1 - (j + 1)) * S4];
            float4 e2 = ep[(size_t)(k - 1 - (j + 2)) * S4];
            float4 e3 = ep[(size_t)(k - 1 - (j + 3)) * S4];
            wsum(c0, dpow(CHUNK * (j + 0)), e0);
            wsum(c1, dpow(CHUNK * (j + 1)), e1);
            wsum(c2, dpow(CHUNK * (j + 2)), e2);
            wsum(c3, dpow(CHUNK * (j + 3)), e3);
        }
        y.x = (c0.x + c1.x) + (c2.x + c3.x);
        y.y = (c0.y + c1.y) + (c2.y + c3.y);
        y.z = (c0.z + c1.z) + (c2.z + c3.z);
        y.w = (c0.w + c1.w) + (c2.w + c3.w);
    } else {
        // 1 <= k <= W: exact sequential fold from E_0 (= true S_0).
        constexpr float dC = dpow(CHUNK);
        y = make_float4(0.f, 0.f, 0.f, 0.f);
        for (int m = 0; m < k; ++m) {
            float4 e = ep[(size_t)m * S4];
            y.x = dC * y.x + e.x;
            y.y = dC * y.y + e.y;
            y.z = dC * y.z + e.z;
            y.w = dC * y.w + e.w;
        }
    }

    // Apply: 8 groups of 8 timesteps, double-buffered in registers so ~8
    // loads stay in flight across the serial chain. All indices static
    // after full unroll (rule: runtime-indexed reg arrays -> scratch).
#pragma unroll
    for (int g = 0; g < 8; ++g) {
        const int cur = g & 1, nxt = cur ^ 1;
        if (g < 7) {
#pragma unroll
            for (int i = 0; i < 8; ++i)
                buf[nxt][i] = xp[(size_t)((g + 1) * 8 + i) * S4];
        }
#pragma unroll
        for (int i = 0; i < 8; ++i) {
            ema_step(y, buf[cur][i]);
            __builtin_nontemporal_store(
                *reinterpret_cast<const f32x4*>(&y),
                reinterpret_cast<f32x4*>(op + (size_t)(g * 8 + i) * S4));
        }
    }
}

// Exact but slow fallback if ws is too small (one block per batch).
__global__ __launch_bounds__(TPB) void ema_seq_kernel(const float* __restrict__ x,
                                                      float* __restrict__ out) {
    const int b = blockIdx.x;
    const int tid = threadIdx.x;
    const float4* xp = reinterpret_cast<const float4*>(x) + (size_t)b * T * S4 + tid;
    float4* op = reinterpret_cast<float4*>(out) + (size_t)b * T * S4 + tid;
    float4 y = xp[0];
    for (int t = 0; t < T; ++t) {
        float4 v = xp[(size_t)t * S4];
        ema_step(y, v);
        op[(size_t)t * S4] = y;
    }
}

extern "C" void kernel_launch(void* const* d_in, const int* in_sizes, int n_in,
                              void* d_out, int out_size, void* d_ws, size_t ws_size,
                              hipStream_t stream) {
    (void)in_sizes; (void)n_in; (void)out_size;
    const float* x = reinterpret_cast<const float*>(d_in[0]);
    float* out = reinterpret_cast<float*>(d_out);

    const size_t need = (size_t)B * K * C * sizeof(float);  // 2 MB
    if (ws_size >= need) {
        float* ends = reinterpret_cast<float*>(d_ws);
        ema_ends<<<dim3(K, B), dim3(TPB), 0, stream>>>(x, ends);
        ema_apply<<<dim3(K, B), dim3(TPB), 0, stream>>>(x, ends, out);
    } else {
        ema_seq_kernel<<<dim3(B), dim3(TPB), 0, stream>>>(x, out);
    }
}